// Round 12
// baseline (135.606 us; speedup 1.0000x reference)
//
#include <hip/hip_runtime.h>
#include <math.h>

#define NB 8
#define NE 128
#define NS 4096
#define CSCALE 0.12751743f   // log2(e)/sqrt(128), folded into Q weights/bias

typedef short s8v __attribute__((ext_vector_type(8)));    // 8 bf16 MFMA A/B frag
typedef float f4v __attribute__((ext_vector_type(4)));    // 16x16 C frag
typedef float f16v __attribute__((ext_vector_type(16)));  // 32x32 C frag
typedef unsigned int u32;
typedef unsigned int u2v __attribute__((ext_vector_type(2)));
typedef __attribute__((address_space(1))) const u32* gp1_t;
typedef __attribute__((address_space(3))) u32* lp3_t;

__device__ __forceinline__ ushort f2bf(float f) {
  union { float f; unsigned u; } v; v.f = f;
  unsigned r = v.u + 0x7fffu + ((v.u >> 16) & 1u);  // RNE
  return (ushort)(r >> 16);
}
__device__ __forceinline__ float bf2f(ushort h) {
  union { unsigned u; float f; } v; v.u = ((unsigned)h) << 16; return v.f;
}
__device__ __forceinline__ void gload_lds16(const void* g, void* l) {
  __builtin_amdgcn_global_load_lds((gp1_t)g, (lp3_t)l, 16, 0, 0);
}
__device__ __forceinline__ u32 cvtpk(float lo, float hi) {
  u32 r;
  asm("v_cvt_pk_bf16_f32 %0, %1, %2" : "=v"(r) : "v"(lo), "v"(hi));
  return r;
}
// split 8 consecutive fp32 into bf16 hi + lo fragments (bf16x3 accuracy)
__device__ __forceinline__ void split8(const float* __restrict__ p, float scale,
                                       s8v& hi, s8v& lo) {
  union { s8v v; ushort u[8]; } H, L;
  #pragma unroll
  for (int i = 0; i < 8; ++i) {
    float v = p[i] * scale;
    ushort h = f2bf(v);
    H.u[i] = h;
    L.u[i] = f2bf(v - bf2f(h));
  }
  hi = H.v; lo = L.v;
}

// ---------------- projection as bf16x3 MFMA GEMM ---------------------------
// outputs: Qn [S][D] (pre-scaled), Kn [S][D], Vt [D][S]; W split done in-reg.
__global__ __launch_bounds__(256, 2) void proj_gemm(
    const float* __restrict__ x,
    const float* __restrict__ Wq, const float* __restrict__ bq,
    const float* __restrict__ Wk, const float* __restrict__ bk,
    const float* __restrict__ Wv, const float* __restrict__ bv,
    ushort* __restrict__ Qn, ushort* __restrict__ Kn, ushort* __restrict__ Vt)
{
  const int tid = threadIdx.x;
  const int wv = tid >> 6, lane = tid & 63;
  const int g = lane >> 4, c = lane & 15;
  const int bid = blockIdx.x;
  const int b = bid & 7;                  // XCD pin
  const int s0 = (bid >> 3) * 64;
  const float* xb = x + (size_t)b * NE * NS;

  __shared__ __align__(16) ushort xh[64][136], xl[64][136];  // x^T tile, hi/lo

  {  // stage: thread owns (s = tid&63, e-chunk), b128 writes
    const int ss = tid & 63, cq = tid >> 6;
    #pragma unroll
    for (int p = 0; p < 4; ++p) {
      const int ch = p * 4 + cq;          // e-chunk 0..15 (8 e each)
      union { s8v v; ushort u[8]; } H, L;
      #pragma unroll
      for (int i = 0; i < 8; ++i) {
        float v = xb[(size_t)(ch * 8 + i) * NS + s0 + ss];
        ushort hi = f2bf(v);
        H.u[i] = hi;
        L.u[i] = f2bf(v - bf2f(hi));
      }
      *(s8v*)&xh[ss][ch * 8] = H.v;
      *(s8v*)&xl[ss][ch * 8] = L.v;
    }
  }
  __syncthreads();

  f4v aq[2][4], ak[2][4], av[2][4];
  #pragma unroll
  for (int i = 0; i < 2; ++i)
    #pragma unroll
    for (int j = 0; j < 4; ++j) {
      aq[i][j] = (f4v){0.f,0.f,0.f,0.f};
      ak[i][j] = (f4v){0.f,0.f,0.f,0.f};
      av[i][j] = (f4v){0.f,0.f,0.f,0.f};
    }

  #pragma unroll
  for (int ks = 0; ks < 4; ++ks) {
    s8v xbh[4], xbl[4];
    #pragma unroll
    for (int st = 0; st < 4; ++st) {
      xbh[st] = *(const s8v*)&xh[st * 16 + c][ks * 32 + g * 8];
      xbl[st] = *(const s8v*)&xl[st * 16 + c][ks * 32 + g * 8];
    }
    #pragma unroll
    for (int ftl = 0; ftl < 2; ++ftl) {
      const int f0 = (wv * 2 + ftl) * 16;
      const size_t wo = (size_t)(f0 + c) * NE + ks * 32 + g * 8;
      s8v qh, ql, kh, kl, vh, vl;
      split8(Wq + wo, CSCALE, qh, ql);
      split8(Wk + wo, 1.0f,   kh, kl);
      split8(Wv + wo, 1.0f,   vh, vl);
      #pragma unroll
      for (int st = 0; st < 4; ++st) {
        // Q (swapped operands -> C[s][f], like K)
        aq[ftl][st] = __builtin_amdgcn_mfma_f32_16x16x32_bf16(xbh[st], qh, aq[ftl][st], 0, 0, 0);
        aq[ftl][st] = __builtin_amdgcn_mfma_f32_16x16x32_bf16(xbl[st], qh, aq[ftl][st], 0, 0, 0);
        aq[ftl][st] = __builtin_amdgcn_mfma_f32_16x16x32_bf16(xbh[st], ql, aq[ftl][st], 0, 0, 0);
        // V (C[f][s])
        av[ftl][st] = __builtin_amdgcn_mfma_f32_16x16x32_bf16(vh, xbh[st], av[ftl][st], 0, 0, 0);
        av[ftl][st] = __builtin_amdgcn_mfma_f32_16x16x32_bf16(vh, xbl[st], av[ftl][st], 0, 0, 0);
        av[ftl][st] = __builtin_amdgcn_mfma_f32_16x16x32_bf16(vl, xbh[st], av[ftl][st], 0, 0, 0);
        // K (C[s][f])
        ak[ftl][st] = __builtin_amdgcn_mfma_f32_16x16x32_bf16(xbh[st], kh, ak[ftl][st], 0, 0, 0);
        ak[ftl][st] = __builtin_amdgcn_mfma_f32_16x16x32_bf16(xbl[st], kh, ak[ftl][st], 0, 0, 0);
        ak[ftl][st] = __builtin_amdgcn_mfma_f32_16x16x32_bf16(xbh[st], kl, ak[ftl][st], 0, 0, 0);
      }
    }
  }

  ushort* Qnb = Qn + (size_t)b * NS * NE;
  ushort* Knb = Kn + (size_t)b * NS * NE;
  ushort* Vtb = Vt + (size_t)b * NE * NS;
  #pragma unroll
  for (int ftl = 0; ftl < 2; ++ftl) {
    const int f0 = (wv * 2 + ftl) * 16;
    #pragma unroll
    for (int r = 0; r < 4; ++r) {            // V: row f = f0+4g+r, col s
      const int f = f0 + 4 * g + r;
      const float bvv = bv[f];
      #pragma unroll
      for (int st = 0; st < 4; ++st)
        Vtb[(size_t)f * NS + s0 + st * 16 + c] = f2bf(av[ftl][st][r] + bvv);
    }
    const float bqv = bq[f0 + c] * CSCALE;   // Q,K: row s = s0+st*16+4g+r, col f = f0+c
    const float bkv = bk[f0 + c];
    #pragma unroll
    for (int st = 0; st < 4; ++st)
      #pragma unroll
      for (int r = 0; r < 4; ++r) {
        const size_t ro = (size_t)(s0 + st * 16 + 4 * g + r) * NE + f0 + c;
        Qnb[ro] = f2bf(aq[ftl][st][r] + bqv);
        Knb[ro] = f2bf(ak[ftl][st][r] + bkv);
      }
  }
}

// ------- flash attention: barrier-free k-loop, wave-private tiles ----------
// Block = 4 waves = 4 k-slices of the SAME 64-q strip. Each wave stages its
// own K (8KB) + V (8KB) single-buffered, pipelined via counted vmcnt with
// split issue points (K loads hide under PV, V loads under QK). No k-loop
// barriers -> waves de-phase freely; 2 independent blocks/CU.
__global__ __launch_bounds__(256, 2) void attn_kernel(
    const ushort* __restrict__ Qn, const ushort* __restrict__ Kn,
    const ushort* __restrict__ Vt, float* __restrict__ out)
{
  const int tid = threadIdx.x;
  const int wv = tid >> 6, lane = tid & 63;
  const int h = lane >> 5, q5 = lane & 31;
  const int slice = wv;                        // k-slice of this wave (0..3)
  const int bid = blockIdx.x;
  const int b = bid & 7;                       // XCD pin: batch b -> XCD b
  const int qw = (bid >> 3) * 64;              // block's 64-q strip (shared)

  const ushort* Qb = Qn + (size_t)b * NS * NE;
  const char*   Kb = (const char*)(Kn + (size_t)b * NS * NE);
  const char*   Vb = (const char*)(Vt + (size_t)b * NE * NS);

  __shared__ __align__(16) char lds[65536];    // 4 waves x (K 8KB + V 8KB)
  __shared__ float lx[4][2][32];               // [slice][u][q5] lsums

  char* myK = lds + wv * 16384;
  char* myV = myK + 8192;

  // Q B-frags: lane holds Q[qw + u*32 + q5][d = dc*16 + h*8 + j]
  s8v qf[2][8];
  #pragma unroll
  for (int u = 0; u < 2; ++u)
    #pragma unroll
    for (int dc = 0; dc < 8; ++dc)
      qf[u][dc] = *(const s8v*)(Qb + (size_t)(qw + u * 32 + q5) * NE + dc * 16 + h * 8);

  // K tile [32 k][256B] xor16 swizzle; V tile [128 d][64B] xor((row>>1)&3)
  auto stageK = [&](int kt) {
    const char* Ksrc = Kb + (size_t)kt * (32 * 256);
    #pragma unroll
    for (int p = 0; p < 8; ++p) {
      const int off = p * 1024;
      const int lo = off + lane * 16;
      const int row = lo >> 8;
      gload_lds16(Ksrc + (lo ^ ((row & 15) << 4)), myK + off);
    }
  };
  auto stageV = [&](int kt) {
    #pragma unroll
    for (int p = 0; p < 8; ++p) {
      const int off = p * 1024;
      const int lo = off + lane * 16;
      const int row = lo >> 6;
      const int inner = (lo & 63) ^ (((row >> 1) & 3) << 4);
      gload_lds16(Vb + (size_t)row * (NS * 2) + kt * 64 + inner, myV + off);
    }
  };

  // fused exp2 -> bf16 frag (8 scores, sums into l)
  auto expfrag8 = [&](float a0, float a1, float a2, float a3,
                      float a4, float a5, float a6, float a7, float& l) -> s8v {
    float p0 = __builtin_amdgcn_exp2f(a0), p1 = __builtin_amdgcn_exp2f(a1);
    float p2 = __builtin_amdgcn_exp2f(a2), p3 = __builtin_amdgcn_exp2f(a3);
    float p4 = __builtin_amdgcn_exp2f(a4), p5 = __builtin_amdgcn_exp2f(a5);
    float p6 = __builtin_amdgcn_exp2f(a6), p7 = __builtin_amdgcn_exp2f(a7);
    l += ((p0 + p1) + (p2 + p3)) + ((p4 + p5) + (p6 + p7));
    u32 A = cvtpk(p0, p1);
    u32 B = cvtpk(p4, p5);
    u32 C = cvtpk(p2, p3);
    u32 D = cvtpk(p6, p7);
    u2v rAB = __builtin_amdgcn_permlane32_swap(A, B, false, false);
    u2v rCD = __builtin_amdgcn_permlane32_swap(C, D, false, false);
    union { s8v v; u32 w[4]; } P;
    P.w[0] = rAB[0]; P.w[1] = rCD[0]; P.w[2] = rAB[1]; P.w[3] = rCD[1];
    return P.v;
  };

  f16v oA[4], oB[4];
  #pragma unroll
  for (int dt = 0; dt < 4; ++dt) {
    oA[dt] = (f16v){0,0,0,0,0,0,0,0,0,0,0,0,0,0,0,0};
    oB[dt] = (f16v){0,0,0,0,0,0,0,0,0,0,0,0,0,0,0,0};
  }
  float lA = 0.f, lB = 0.f;

  const int kt0 = slice * 32;
  stageK(kt0);                 // 8 loads in flight
  stageV(kt0);                 // +8

  #pragma unroll 1
  for (int t = 0; t < 32; ++t) {
    const int ktn = kt0 + (t + 1 < 32 ? t + 1 : 31);  // uniform re-issue on last

    // ---- wait K(t) resident (V(t) may still be in flight: 8 newer loads)
    asm volatile("s_waitcnt vmcnt(8)" ::: "memory");
    __builtin_amdgcn_sched_barrier(0);

    // ---- S^T[k][q] = K . Q^T for both q-subtiles
    f16v sA = (f16v){0,0,0,0,0,0,0,0,0,0,0,0,0,0,0,0};
    f16v sB = (f16v){0,0,0,0,0,0,0,0,0,0,0,0,0,0,0,0};
    __builtin_amdgcn_s_setprio(1);
    #pragma unroll
    for (int dc = 0; dc < 8; ++dc) {
      s8v kf = *(const s8v*)(myK + q5 * 256 + ((dc * 32 + h * 16) ^ ((q5 & 15) << 4)));
      sA = __builtin_amdgcn_mfma_f32_32x32x16_bf16(kf, qf[0][dc], sA, 0, 0, 0);
      sB = __builtin_amdgcn_mfma_f32_32x32x16_bf16(kf, qf[1][dc], sB, 0, 0, 0);
    }
    __builtin_amdgcn_s_setprio(0);

    // ---- all K ds_reads complete -> safe to overwrite K buffer; issue K(t+1)
    asm volatile("s_waitcnt lgkmcnt(0)" ::: "memory");
    __builtin_amdgcn_sched_barrier(0);
    stageK(ktn);

    // ---- wait V(t) resident (K(t+1) in flight: 8 newer loads)
    asm volatile("s_waitcnt vmcnt(8)" ::: "memory");
    __builtin_amdgcn_sched_barrier(0);

    // ---- softmax numerators fused into PV frags
    #pragma unroll
    for (int ksl = 0; ksl < 2; ++ksl) {
      s8v PA, PB;
      if (ksl == 0) {
        PA = expfrag8(sA[0], sA[1], sA[2], sA[3], sA[4], sA[5], sA[6], sA[7], lA);
        PB = expfrag8(sB[0], sB[1], sB[2], sB[3], sB[4], sB[5], sB[6], sB[7], lB);
      } else {
        PA = expfrag8(sA[8], sA[9], sA[10], sA[11], sA[12], sA[13], sA[14], sA[15], lA);
        PB = expfrag8(sB[8], sB[9], sB[10], sB[11], sB[12], sB[13], sB[14], sB[15], lB);
      }
      __builtin_amdgcn_s_setprio(1);
      #pragma unroll
      for (int dt = 0; dt < 4; ++dt) {
        const int vrow = dt * 32 + q5;
        s8v vf = *(const s8v*)(myV + vrow * 64 +
                               ((ksl * 32 + h * 16) ^ (((q5 >> 1) & 3) << 4)));
        oA[dt] = __builtin_amdgcn_mfma_f32_32x32x16_bf16(vf, PA, oA[dt], 0, 0, 0);
        oB[dt] = __builtin_amdgcn_mfma_f32_32x32x16_bf16(vf, PB, oB[dt], 0, 0, 0);
      }
      __builtin_amdgcn_s_setprio(0);
    }

    // ---- all V ds_reads complete -> safe to overwrite V buffer; issue V(t+1)
    asm volatile("s_waitcnt lgkmcnt(0)" ::: "memory");
    __builtin_amdgcn_sched_barrier(0);
    stageV(ktn);
  }

  // ---- epilogue: 4-slice combine (all waves same 64 q) --------------------
  lA += __shfl_xor(lA, 32);
  lB += __shfl_xor(lB, 32);
  if (h == 0) { lx[slice][0][q5] = lA; lx[slice][1][q5] = lB; }
  float* cb = (float*)lds;                 // 64 KB dead; need 32 KB
  __syncthreads();                         // all waves done with their tiles
  if (slice == 0) {                        // init with slice 0's partial
    #pragma unroll
    for (int dt = 0; dt < 4; ++dt)
      #pragma unroll
      for (int r = 0; r < 16; ++r) {
        const int e = dt * 32 + (r & 3) + 8 * (r >> 2) + 4 * h;
        cb[e * 64 + q5]      = oA[dt][r];
        cb[e * 64 + 32 + q5] = oB[dt][r];
      }
  }
  __syncthreads();
  #pragma unroll 1
  for (int sl = 1; sl < 4; ++sl) {         // barrier-ordered accumulation
    if (slice == sl) {
      #pragma unroll
      for (int dt = 0; dt < 4; ++dt)
        #pragma unroll
        for (int r = 0; r < 16; ++r) {
          const int e = dt * 32 + (r & 3) + 8 * (r >> 2) + 4 * h;
          cb[e * 64 + q5]      += oA[dt][r];
          cb[e * 64 + 32 + q5] += oB[dt][r];
        }
    }
    __syncthreads();
  }
  if (slice == 0) {                        // normalize + store
    const float rA = 1.0f / (lx[0][0][q5] + lx[1][0][q5] +
                             lx[2][0][q5] + lx[3][0][q5]);
    const float rB = 1.0f / (lx[0][1][q5] + lx[1][1][q5] +
                             lx[2][1][q5] + lx[3][1][q5]);
    float* ob = out + (size_t)b * NE * NS;
    #pragma unroll
    for (int dt = 0; dt < 4; ++dt)
      #pragma unroll
      for (int r = 0; r < 16; ++r) {
        const int e = dt * 32 + (r & 3) + 8 * (r >> 2) + 4 * h;
        ob[(size_t)e * NS + qw + q5]      = cb[e * 64 + q5] * rA;
        ob[(size_t)e * NS + qw + 32 + q5] = cb[e * 64 + 32 + q5] * rB;
      }
  }
}

extern "C" void kernel_launch(void* const* d_in, const int* in_sizes, int n_in,
                              void* d_out, int out_size, void* d_ws, size_t ws_size,
                              hipStream_t stream) {
  (void)in_sizes; (void)n_in; (void)out_size; (void)ws_size;
  const float* x  = (const float*)d_in[0];
  const float* Wq = (const float*)d_in[1];
  const float* bq = (const float*)d_in[2];
  const float* Wk = (const float*)d_in[3];
  const float* bk = (const float*)d_in[4];
  const float* Wv = (const float*)d_in[5];
  const float* bv = (const float*)d_in[6];
  float* out = (float*)d_out;

  ushort* Qn = (ushort*)d_ws;                      // [B][S][D] bf16, 8 MB
  ushort* Kn = Qn + (size_t)NB * NS * NE;          // [B][S][D] bf16, 8 MB
  ushort* Vt = Kn + (size_t)NB * NS * NE;          // [B][D][S] bf16, 8 MB

  proj_gemm<<<dim3(NS / 64 * NB), 256, 0, stream>>>(x, Wq, bq, Wk, bk, Wv, bv, Qn, Kn, Vt);
  attn_kernel<<<dim3(NS / 64 * NB), 256, 0, stream>>>(Qn, Kn, Vt, out);
}

// Round 13
// 101.917 us; speedup vs baseline: 1.3306x; 1.3306x over previous
//
#include <hip/hip_runtime.h>
#include <math.h>

#define NB 8
#define NE 128
#define NS 4096
#define CSCALE 0.12751743f   // log2(e)/sqrt(128), folded into Q weights/bias

typedef short s8v __attribute__((ext_vector_type(8)));    // 8 bf16 MFMA A/B frag
typedef float f4v __attribute__((ext_vector_type(4)));    // 16x16 C frag
typedef float f16v __attribute__((ext_vector_type(16)));  // 32x32 C frag
typedef unsigned int u32;
typedef unsigned int u2v __attribute__((ext_vector_type(2)));
typedef __attribute__((address_space(1))) const u32* gp1_t;
typedef __attribute__((address_space(3))) u32* lp3_t;

__device__ __forceinline__ ushort f2bf(float f) {
  union { float f; unsigned u; } v; v.f = f;
  unsigned r = v.u + 0x7fffu + ((v.u >> 16) & 1u);  // RNE
  return (ushort)(r >> 16);
}
__device__ __forceinline__ float bf2f(ushort h) {
  union { unsigned u; float f; } v; v.u = ((unsigned)h) << 16; return v.f;
}
__device__ __forceinline__ void gload_lds16(const void* g, void* l) {
  __builtin_amdgcn_global_load_lds((gp1_t)g, (lp3_t)l, 16, 0, 0);
}
__device__ __forceinline__ u32 cvtpk(float lo, float hi) {
  u32 r;
  asm("v_cvt_pk_bf16_f32 %0, %1, %2" : "=v"(r) : "v"(lo), "v"(hi));
  return r;
}
// split 8 consecutive fp32 into bf16 hi + lo fragments (bf16x3 accuracy)
__device__ __forceinline__ void split8(const float* __restrict__ p, float scale,
                                       s8v& hi, s8v& lo) {
  union { s8v v; ushort u[8]; } H, L;
  #pragma unroll
  for (int i = 0; i < 8; ++i) {
    float v = p[i] * scale;
    ushort h = f2bf(v);
    H.u[i] = h;
    L.u[i] = f2bf(v - bf2f(h));
  }
  hi = H.v; lo = L.v;
}

// ---------------- projection as bf16x3 MFMA GEMM ---------------------------
__global__ __launch_bounds__(256, 2) void proj_gemm(
    const float* __restrict__ x,
    const float* __restrict__ Wq, const float* __restrict__ bq,
    const float* __restrict__ Wk, const float* __restrict__ bk,
    const float* __restrict__ Wv, const float* __restrict__ bv,
    ushort* __restrict__ Qn, ushort* __restrict__ Kn, ushort* __restrict__ Vt)
{
  const int tid = threadIdx.x;
  const int wv = tid >> 6, lane = tid & 63;
  const int g = lane >> 4, c = lane & 15;
  const int bid = blockIdx.x;
  const int b = bid & 7;                  // XCD pin
  const int s0 = (bid >> 3) * 64;
  const float* xb = x + (size_t)b * NE * NS;

  __shared__ __align__(16) ushort xh[64][136], xl[64][136];  // x^T tile, hi/lo

  {
    const int ss = tid & 63, cq = tid >> 6;
    #pragma unroll
    for (int p = 0; p < 4; ++p) {
      const int ch = p * 4 + cq;
      union { s8v v; ushort u[8]; } H, L;
      #pragma unroll
      for (int i = 0; i < 8; ++i) {
        float v = xb[(size_t)(ch * 8 + i) * NS + s0 + ss];
        ushort hi = f2bf(v);
        H.u[i] = hi;
        L.u[i] = f2bf(v - bf2f(hi));
      }
      *(s8v*)&xh[ss][ch * 8] = H.v;
      *(s8v*)&xl[ss][ch * 8] = L.v;
    }
  }
  __syncthreads();

  f4v aq[2][4], ak[2][4], av[2][4];
  #pragma unroll
  for (int i = 0; i < 2; ++i)
    #pragma unroll
    for (int j = 0; j < 4; ++j) {
      aq[i][j] = (f4v){0.f,0.f,0.f,0.f};
      ak[i][j] = (f4v){0.f,0.f,0.f,0.f};
      av[i][j] = (f4v){0.f,0.f,0.f,0.f};
    }

  #pragma unroll
  for (int ks = 0; ks < 4; ++ks) {
    s8v xbh[4], xbl[4];
    #pragma unroll
    for (int st = 0; st < 4; ++st) {
      xbh[st] = *(const s8v*)&xh[st * 16 + c][ks * 32 + g * 8];
      xbl[st] = *(const s8v*)&xl[st * 16 + c][ks * 32 + g * 8];
    }
    #pragma unroll
    for (int ftl = 0; ftl < 2; ++ftl) {
      const int f0 = (wv * 2 + ftl) * 16;
      const size_t wo = (size_t)(f0 + c) * NE + ks * 32 + g * 8;
      s8v qh, ql, kh, kl, vh, vl;
      split8(Wq + wo, CSCALE, qh, ql);
      split8(Wk + wo, 1.0f,   kh, kl);
      split8(Wv + wo, 1.0f,   vh, vl);
      #pragma unroll
      for (int st = 0; st < 4; ++st) {
        aq[ftl][st] = __builtin_amdgcn_mfma_f32_16x16x32_bf16(xbh[st], qh, aq[ftl][st], 0, 0, 0);
        aq[ftl][st] = __builtin_amdgcn_mfma_f32_16x16x32_bf16(xbl[st], qh, aq[ftl][st], 0, 0, 0);
        aq[ftl][st] = __builtin_amdgcn_mfma_f32_16x16x32_bf16(xbh[st], ql, aq[ftl][st], 0, 0, 0);
        av[ftl][st] = __builtin_amdgcn_mfma_f32_16x16x32_bf16(vh, xbh[st], av[ftl][st], 0, 0, 0);
        av[ftl][st] = __builtin_amdgcn_mfma_f32_16x16x32_bf16(vh, xbl[st], av[ftl][st], 0, 0, 0);
        av[ftl][st] = __builtin_amdgcn_mfma_f32_16x16x32_bf16(vl, xbh[st], av[ftl][st], 0, 0, 0);
        ak[ftl][st] = __builtin_amdgcn_mfma_f32_16x16x32_bf16(xbh[st], kh, ak[ftl][st], 0, 0, 0);
        ak[ftl][st] = __builtin_amdgcn_mfma_f32_16x16x32_bf16(xbl[st], kh, ak[ftl][st], 0, 0, 0);
        ak[ftl][st] = __builtin_amdgcn_mfma_f32_16x16x32_bf16(xbh[st], kl, ak[ftl][st], 0, 0, 0);
      }
    }
  }

  ushort* Qnb = Qn + (size_t)b * NS * NE;
  ushort* Knb = Kn + (size_t)b * NS * NE;
  ushort* Vtb = Vt + (size_t)b * NE * NS;
  #pragma unroll
  for (int ftl = 0; ftl < 2; ++ftl) {
    const int f0 = (wv * 2 + ftl) * 16;
    #pragma unroll
    for (int r = 0; r < 4; ++r) {
      const int f = f0 + 4 * g + r;
      const float bvv = bv[f];
      #pragma unroll
      for (int st = 0; st < 4; ++st)
        Vtb[(size_t)f * NS + s0 + st * 16 + c] = f2bf(av[ftl][st][r] + bvv);
    }
    const float bqv = bq[f0 + c] * CSCALE;
    const float bkv = bk[f0 + c];
    #pragma unroll
    for (int st = 0; st < 4; ++st)
      #pragma unroll
      for (int r = 0; r < 4; ++r) {
        const size_t ro = (size_t)(s0 + st * 16 + 4 * g + r) * NE + f0 + c;
        Qnb[ro] = f2bf(aq[ftl][st][r] + bqv);
        Knb[ro] = f2bf(ak[ftl][st][r] + bkv);
      }
  }
}

// ------- flash attention: 8 warps x 32q, in-block k-split=2, KVB=64 --------
// warps 0-3: k-slice 0, warps 4-7: k-slice 1; warp sub w&3 owns 32-q strip.
// Shared dbuf K/V tiles per slice (32 KB each), staged by the slice's 4 warps
// (8 gload_lds each). Raw s_barrier; single long-distance vmcnt(0) per tile.
__global__ __launch_bounds__(512, 2) void attn_kernel(
    const ushort* __restrict__ Qn, const ushort* __restrict__ Kn,
    const ushort* __restrict__ Vt, float* __restrict__ out)
{
  const int tid = threadIdx.x;
  const int w = tid >> 6, lane = tid & 63;
  const int h = lane >> 5, q5 = lane & 31;
  const int slice = w >> 2;                    // k-slice (0/1)
  const int sub = w & 3;                       // q-strip within block
  const int bid = blockIdx.x;
  const int b = bid & 7;                       // XCD pin
  const int qw = (bid >> 3) * 128 + sub * 32;  // warp's 32-q strip

  const ushort* Qb = Qn + (size_t)b * NS * NE;
  const char*   Kb = (const char*)(Kn + (size_t)b * NS * NE);
  const char*   Vb = (const char*)(Vt + (size_t)b * NE * NS);

  __shared__ __align__(16) char lds[131072];   // [slice][buf][K 16K | V 16K]
  __shared__ float lx[2][4][32];               // [slice][sub][q5] lsum

  auto Kbuf = [&](int bf) -> char* { return lds + slice * 65536 + bf * 32768; };
  auto Vbuf = [&](int bf) -> char* { return Kbuf(bf) + 16384; };

  // Q B-frags (proven R6 layout): lane holds Q[qw+q5][dc*16 + h*8 + j]
  s8v qf[8];
  #pragma unroll
  for (int dc = 0; dc < 8; ++dc)
    qf[dc] = *(const s8v*)(Qb + (size_t)(qw + q5) * NE + dc * 16 + h * 8);

  // stage tile t of own slice: subs 0,1 -> K halves; subs 2,3 -> V halves
  auto stage = [&](int bf, int t) {
    const int kt = slice * 32 + t;
    if (sub < 2) {
      const char* Ksrc = Kb + (size_t)kt * (64 * 256);   // contiguous 16KB
      char* dst = Kbuf(bf);
      const int base = sub * 8192;
      #pragma unroll
      for (int p = 0; p < 8; ++p) {
        const int off = base + p * 1024;
        const int lo = off + lane * 16;
        const int row = lo >> 8;                         // k row (256B)
        gload_lds16(Ksrc + (lo ^ ((row & 15) << 4)), dst + off);
      }
    } else {
      char* dst = Vbuf(bf);
      const int base = (sub - 2) * 8192;
      #pragma unroll
      for (int p = 0; p < 8; ++p) {
        const int off = base + p * 1024;
        const int lo = off + lane * 16;
        const int row = lo >> 7;                         // d row (128B)
        const int inner = (lo & 127) ^ ((row & 7) << 4);
        gload_lds16(Vb + (size_t)row * (NS * 2) + kt * 128 + inner, dst + off);
      }
    }
  };

  // fused exp2 -> bf16 PV frag (proven R11)
  auto expfrag8 = [&](float a0, float a1, float a2, float a3,
                      float a4, float a5, float a6, float a7, float& l) -> s8v {
    float p0 = __builtin_amdgcn_exp2f(a0), p1 = __builtin_amdgcn_exp2f(a1);
    float p2 = __builtin_amdgcn_exp2f(a2), p3 = __builtin_amdgcn_exp2f(a3);
    float p4 = __builtin_amdgcn_exp2f(a4), p5 = __builtin_amdgcn_exp2f(a5);
    float p6 = __builtin_amdgcn_exp2f(a6), p7 = __builtin_amdgcn_exp2f(a7);
    l += ((p0 + p1) + (p2 + p3)) + ((p4 + p5) + (p6 + p7));
    u32 A = cvtpk(p0, p1);
    u32 B = cvtpk(p4, p5);
    u32 C = cvtpk(p2, p3);
    u32 D = cvtpk(p6, p7);
    u2v rAB = __builtin_amdgcn_permlane32_swap(A, B, false, false);
    u2v rCD = __builtin_amdgcn_permlane32_swap(C, D, false, false);
    union { s8v v; u32 wd[4]; } P;
    P.wd[0] = rAB[0]; P.wd[1] = rCD[0]; P.wd[2] = rAB[1]; P.wd[3] = rCD[1];
    return P.v;
  };

  f16v o[4];
  #pragma unroll
  for (int dt = 0; dt < 4; ++dt)
    o[dt] = (f16v){0,0,0,0,0,0,0,0,0,0,0,0,0,0,0,0};
  float lsum = 0.f;

  stage(0, 0);
  asm volatile("s_waitcnt vmcnt(0)" ::: "memory");
  __builtin_amdgcn_sched_barrier(0);
  __builtin_amdgcn_s_barrier();

  #pragma unroll 1
  for (int t = 0; t < 32; ++t) {
    const int cur = t & 1;
    if (t + 1 < 32) stage(cur ^ 1, t + 1);   // waited at end of this tile
    const char* bK = Kbuf(cur);
    const char* bV = Vbuf(cur);

    // ---- QK: S^T[k][q] = K . Q^T, two 32-k groups (compiler-paced lgkmcnt)
    f16v s0 = (f16v){0,0,0,0,0,0,0,0,0,0,0,0,0,0,0,0};
    f16v s1 = (f16v){0,0,0,0,0,0,0,0,0,0,0,0,0,0,0,0};
    __builtin_amdgcn_s_setprio(1);
    #pragma unroll
    for (int dc = 0; dc < 8; ++dc) {
      s8v kf0 = *(const s8v*)(bK + (q5) * 256      + ((dc * 32 + h * 16) ^ ((q5 & 15) << 4)));
      s8v kf1 = *(const s8v*)(bK + (32 + q5) * 256 + ((dc * 32 + h * 16) ^ ((q5 & 15) << 4)));
      s0 = __builtin_amdgcn_mfma_f32_32x32x16_bf16(kf0, qf[dc], s0, 0, 0, 0);
      s1 = __builtin_amdgcn_mfma_f32_32x32x16_bf16(kf1, qf[dc], s1, 0, 0, 0);
    }
    __builtin_amdgcn_s_setprio(0);

    // ---- SM fused into PV frags; 4 k-slices of 16
    #pragma unroll
    for (int ks = 0; ks < 4; ++ks) {
      s8v P;
      if (ks == 0)      P = expfrag8(s0[0], s0[1], s0[2], s0[3], s0[4], s0[5], s0[6], s0[7], lsum);
      else if (ks == 1) P = expfrag8(s0[8], s0[9], s0[10], s0[11], s0[12], s0[13], s0[14], s0[15], lsum);
      else if (ks == 2) P = expfrag8(s1[0], s1[1], s1[2], s1[3], s1[4], s1[5], s1[6], s1[7], lsum);
      else              P = expfrag8(s1[8], s1[9], s1[10], s1[11], s1[12], s1[13], s1[14], s1[15], lsum);
      __builtin_amdgcn_s_setprio(1);
      #pragma unroll
      for (int dt = 0; dt < 4; ++dt) {
        s8v vf = *(const s8v*)(bV + (dt * 32 + q5) * 128 +
                               ((ks * 32 + h * 16) ^ ((q5 & 7) << 4)));
        o[dt] = __builtin_amdgcn_mfma_f32_32x32x16_bf16(vf, P, o[dt], 0, 0, 0);
      }
      __builtin_amdgcn_s_setprio(0);
    }

    // ---- end of tile: my ds_reads done; next tile resident; converge
    asm volatile("s_waitcnt lgkmcnt(0)" ::: "memory");
    __builtin_amdgcn_sched_barrier(0);
    asm volatile("s_waitcnt vmcnt(0)" ::: "memory");   // issued a full tile ago
    __builtin_amdgcn_sched_barrier(0);
    __builtin_amdgcn_s_barrier();
  }

  // ---- combine the two k-slices via (dead) LDS ----------------------------
  lsum += __shfl_xor(lsum, 32);
  if (h == 0) lx[slice][sub][q5] = lsum;
  float* cb = (float*)lds;                 // 64 KB: [sub][128 e][32 q]
  __syncthreads();
  if (slice == 1) {
    #pragma unroll
    for (int dt = 0; dt < 4; ++dt)
      #pragma unroll
      for (int r = 0; r < 16; ++r) {
        const int e = dt * 32 + (r & 3) + 8 * (r >> 2) + 4 * h;
        cb[sub * 4096 + e * 32 + q5] = o[dt][r];
      }
  }
  __syncthreads();
  if (slice == 0) {
    const float rinv = 1.0f / (lx[0][sub][q5] + lx[1][sub][q5]);
    float* ob = out + (size_t)b * NE * NS;
    #pragma unroll
    for (int dt = 0; dt < 4; ++dt)
      #pragma unroll
      for (int r = 0; r < 16; ++r) {
        const int e = dt * 32 + (r & 3) + 8 * (r >> 2) + 4 * h;
        ob[(size_t)e * NS + qw + q5] =
            (o[dt][r] + cb[sub * 4096 + e * 32 + q5]) * rinv;
      }
  }
}

extern "C" void kernel_launch(void* const* d_in, const int* in_sizes, int n_in,
                              void* d_out, int out_size, void* d_ws, size_t ws_size,
                              hipStream_t stream) {
  (void)in_sizes; (void)n_in; (void)out_size; (void)ws_size;
  const float* x  = (const float*)d_in[0];
  const float* Wq = (const float*)d_in[1];
  const float* bq = (const float*)d_in[2];
  const float* Wk = (const float*)d_in[3];
  const float* bk = (const float*)d_in[4];
  const float* Wv = (const float*)d_in[5];
  const float* bv = (const float*)d_in[6];
  float* out = (float*)d_out;

  ushort* Qn = (ushort*)d_ws;                      // [B][S][D] bf16, 8 MB
  ushort* Kn = Qn + (size_t)NB * NS * NE;          // [B][S][D] bf16, 8 MB
  ushort* Vt = Kn + (size_t)NB * NS * NE;          // [B][D][S] bf16, 8 MB

  proj_gemm<<<dim3(NS / 64 * NB), 256, 0, stream>>>(x, Wq, bq, Wk, bk, Wv, bv, Qn, Kn, Vt);
  attn_kernel<<<dim3(NS / 128 * NB), 512, 0, stream>>>(Qn, Kn, Vt, out);
}

// Round 14
// 100.700 us; speedup vs baseline: 1.3466x; 1.0121x over previous
//
#include <hip/hip_runtime.h>
#include <math.h>

#define NB 8
#define NE 128
#define NS 4096
#define CSCALE 0.12751743f   // log2(e)/sqrt(128), folded into Q weights/bias

typedef short s8v __attribute__((ext_vector_type(8)));    // 8 bf16 MFMA A/B frag
typedef float f4v __attribute__((ext_vector_type(4)));    // 16x16 C frag
typedef float f16v __attribute__((ext_vector_type(16)));  // 32x32 C frag
typedef unsigned int u32;
typedef unsigned int u2v __attribute__((ext_vector_type(2)));
typedef __attribute__((address_space(1))) const u32* gp1_t;
typedef __attribute__((address_space(3))) u32* lp3_t;

__device__ __forceinline__ ushort f2bf(float f) {
  union { float f; unsigned u; } v; v.f = f;
  unsigned r = v.u + 0x7fffu + ((v.u >> 16) & 1u);  // RNE
  return (ushort)(r >> 16);
}
__device__ __forceinline__ float bf2f(ushort h) {
  union { unsigned u; float f; } v; v.u = ((unsigned)h) << 16; return v.f;
}
__device__ __forceinline__ void gload_lds16(const void* g, void* l) {
  __builtin_amdgcn_global_load_lds((gp1_t)g, (lp3_t)l, 16, 0, 0);
}
__device__ __forceinline__ u32 cvtpk(float lo, float hi) {
  u32 r;
  asm("v_cvt_pk_bf16_f32 %0, %1, %2" : "=v"(r) : "v"(lo), "v"(hi));
  return r;
}
// split 8 consecutive fp32 into bf16 hi + lo fragments (bf16x3 accuracy)
__device__ __forceinline__ void split8(const float* __restrict__ p, float scale,
                                       s8v& hi, s8v& lo) {
  union { s8v v; ushort u[8]; } H, L;
  #pragma unroll
  for (int i = 0; i < 8; ++i) {
    float v = p[i] * scale;
    ushort h = f2bf(v);
    H.u[i] = h;
    L.u[i] = f2bf(v - bf2f(h));
  }
  hi = H.v; lo = L.v;
}

// ---------------- projection as bf16x3 MFMA GEMM ---------------------------
__global__ __launch_bounds__(256, 2) void proj_gemm(
    const float* __restrict__ x,
    const float* __restrict__ Wq, const float* __restrict__ bq,
    const float* __restrict__ Wk, const float* __restrict__ bk,
    const float* __restrict__ Wv, const float* __restrict__ bv,
    ushort* __restrict__ Qn, ushort* __restrict__ Kn, ushort* __restrict__ Vt)
{
  const int tid = threadIdx.x;
  const int wv = tid >> 6, lane = tid & 63;
  const int g = lane >> 4, c = lane & 15;
  const int bid = blockIdx.x;
  const int b = bid & 7;                  // XCD pin
  const int s0 = (bid >> 3) * 64;
  const float* xb = x + (size_t)b * NE * NS;

  __shared__ __align__(16) ushort xh[64][136], xl[64][136];  // x^T tile, hi/lo

  {
    const int ss = tid & 63, cq = tid >> 6;
    #pragma unroll
    for (int p = 0; p < 4; ++p) {
      const int ch = p * 4 + cq;
      union { s8v v; ushort u[8]; } H, L;
      #pragma unroll
      for (int i = 0; i < 8; ++i) {
        float v = xb[(size_t)(ch * 8 + i) * NS + s0 + ss];
        ushort hi = f2bf(v);
        H.u[i] = hi;
        L.u[i] = f2bf(v - bf2f(hi));
      }
      *(s8v*)&xh[ss][ch * 8] = H.v;
      *(s8v*)&xl[ss][ch * 8] = L.v;
    }
  }
  __syncthreads();

  f4v aq[2][4], ak[2][4], av[2][4];
  #pragma unroll
  for (int i = 0; i < 2; ++i)
    #pragma unroll
    for (int j = 0; j < 4; ++j) {
      aq[i][j] = (f4v){0.f,0.f,0.f,0.f};
      ak[i][j] = (f4v){0.f,0.f,0.f,0.f};
      av[i][j] = (f4v){0.f,0.f,0.f,0.f};
    }

  #pragma unroll
  for (int ks = 0; ks < 4; ++ks) {
    s8v xbh[4], xbl[4];
    #pragma unroll
    for (int st = 0; st < 4; ++st) {
      xbh[st] = *(const s8v*)&xh[st * 16 + c][ks * 32 + g * 8];
      xbl[st] = *(const s8v*)&xl[st * 16 + c][ks * 32 + g * 8];
    }
    #pragma unroll
    for (int ftl = 0; ftl < 2; ++ftl) {
      const int f0 = (wv * 2 + ftl) * 16;
      const size_t wo = (size_t)(f0 + c) * NE + ks * 32 + g * 8;
      s8v qh, ql, kh, kl, vh, vl;
      split8(Wq + wo, CSCALE, qh, ql);
      split8(Wk + wo, 1.0f,   kh, kl);
      split8(Wv + wo, 1.0f,   vh, vl);
      #pragma unroll
      for (int st = 0; st < 4; ++st) {
        aq[ftl][st] = __builtin_amdgcn_mfma_f32_16x16x32_bf16(xbh[st], qh, aq[ftl][st], 0, 0, 0);
        aq[ftl][st] = __builtin_amdgcn_mfma_f32_16x16x32_bf16(xbl[st], qh, aq[ftl][st], 0, 0, 0);
        aq[ftl][st] = __builtin_amdgcn_mfma_f32_16x16x32_bf16(xbh[st], ql, aq[ftl][st], 0, 0, 0);
        av[ftl][st] = __builtin_amdgcn_mfma_f32_16x16x32_bf16(vh, xbh[st], av[ftl][st], 0, 0, 0);
        av[ftl][st] = __builtin_amdgcn_mfma_f32_16x16x32_bf16(vh, xbl[st], av[ftl][st], 0, 0, 0);
        av[ftl][st] = __builtin_amdgcn_mfma_f32_16x16x32_bf16(vl, xbh[st], av[ftl][st], 0, 0, 0);
        ak[ftl][st] = __builtin_amdgcn_mfma_f32_16x16x32_bf16(xbh[st], kh, ak[ftl][st], 0, 0, 0);
        ak[ftl][st] = __builtin_amdgcn_mfma_f32_16x16x32_bf16(xbl[st], kh, ak[ftl][st], 0, 0, 0);
        ak[ftl][st] = __builtin_amdgcn_mfma_f32_16x16x32_bf16(xbh[st], kl, ak[ftl][st], 0, 0, 0);
      }
    }
  }

  ushort* Qnb = Qn + (size_t)b * NS * NE;
  ushort* Knb = Kn + (size_t)b * NS * NE;
  ushort* Vtb = Vt + (size_t)b * NE * NS;
  #pragma unroll
  for (int ftl = 0; ftl < 2; ++ftl) {
    const int f0 = (wv * 2 + ftl) * 16;
    #pragma unroll
    for (int r = 0; r < 4; ++r) {
      const int f = f0 + 4 * g + r;
      const float bvv = bv[f];
      #pragma unroll
      for (int st = 0; st < 4; ++st)
        Vtb[(size_t)f * NS + s0 + st * 16 + c] = f2bf(av[ftl][st][r] + bvv);
    }
    const float bqv = bq[f0 + c] * CSCALE;
    const float bkv = bk[f0 + c];
    #pragma unroll
    for (int st = 0; st < 4; ++st)
      #pragma unroll
      for (int r = 0; r < 4; ++r) {
        const size_t ro = (size_t)(s0 + st * 16 + 4 * g + r) * NE + f0 + c;
        Qnb[ro] = f2bf(aq[ftl][st][r] + bqv);
        Knb[ro] = f2bf(ak[ftl][st][r] + bkv);
      }
  }
}

// ------- flash attention: 8 warps x 32q, k-split=2, KVB=64, SW-pipelined ---
// Body: QK(t) || PV(t-1) -> SM(t)->P regs. V staged 0-ahead (V(t) during
// tile t, read at t+1): read buf (t-1)&1, write buf t&1 -> clean dbuf.
// V tile re-packed [64 rows][256B] (two d-halves/row) xor16 = 2-way free.
__global__ __launch_bounds__(512, 2) void attn_kernel(
    const ushort* __restrict__ Qn, const ushort* __restrict__ Kn,
    const ushort* __restrict__ Vt, float* __restrict__ out)
{
  const int tid = threadIdx.x;
  const int w = tid >> 6, lane = tid & 63;
  const int h = lane >> 5, q5 = lane & 31;
  const int slice = w >> 2;                    // k-slice (0/1)
  const int sub = w & 3;                       // q-strip within block
  const int bid = blockIdx.x;
  const int b = bid & 7;                       // XCD pin
  const int qw = (bid >> 3) * 128 + sub * 32;  // warp's 32-q strip

  const ushort* Qb = Qn + (size_t)b * NS * NE;
  const char*   Kb = (const char*)(Kn + (size_t)b * NS * NE);
  const char*   Vb = (const char*)(Vt + (size_t)b * NE * NS);

  __shared__ __align__(16) char lds[131072];   // [slice][buf][K 16K | V 16K]
  __shared__ float lx[2][4][32];               // [slice][sub][q5] lsum

  auto Kbuf = [&](int bf) -> char* { return lds + slice * 65536 + bf * 32768; };
  auto Vbuf = [&](int bf) -> char* { return Kbuf(bf) + 16384; };

  // Q B-frags: lane holds Q[qw+q5][dc*16 + h*8 + j]
  s8v qf[8];
  #pragma unroll
  for (int dc = 0; dc < 8; ++dc)
    qf[dc] = *(const s8v*)(Qb + (size_t)(qw + q5) * NE + dc * 16 + h * 8);

  // stage K tile t into buf (subs 0,1); [64 k][256B] xor16
  auto stageK = [&](int bf, int t) {
    if (sub < 2) {
      const int kt = slice * 32 + t;
      const char* Ksrc = Kb + (size_t)kt * (64 * 256);   // contiguous 16KB
      char* dst = Kbuf(bf);
      const int base = sub * 8192;
      #pragma unroll
      for (int p = 0; p < 8; ++p) {
        const int off = base + p * 1024;
        const int lo = off + lane * 16;
        const int row = lo >> 8;
        gload_lds16(Ksrc + (lo ^ ((row & 15) << 4)), dst + off);
      }
    }
  };
  // stage V tile t into buf (subs 2,3); [64 rows][256B]: row r holds
  // d=r (bytes 0..127) and d=r+64 (bytes 128..255), xor16 swizzle
  auto stageV = [&](int bf, int t) {
    if (sub >= 2) {
      const int kt = slice * 32 + t;
      char* dst = Vbuf(bf);
      const int base = (sub - 2) * 8192;
      #pragma unroll
      for (int p = 0; p < 8; ++p) {
        const int off = base + p * 1024;
        const int lo = off + lane * 16;
        const int row = lo >> 8;
        const int inner = (lo & 255) ^ ((row & 15) << 4);
        const int d = row + (inner >> 7) * 64;
        gload_lds16(Vb + (size_t)d * (NS * 2) + kt * 128 + (inner & 127), dst + off);
      }
    }
  };

  // fused exp2 -> bf16 PV frag
  auto expfrag8 = [&](float a0, float a1, float a2, float a3,
                      float a4, float a5, float a6, float a7, float& l) -> s8v {
    float p0 = __builtin_amdgcn_exp2f(a0), p1 = __builtin_amdgcn_exp2f(a1);
    float p2 = __builtin_amdgcn_exp2f(a2), p3 = __builtin_amdgcn_exp2f(a3);
    float p4 = __builtin_amdgcn_exp2f(a4), p5 = __builtin_amdgcn_exp2f(a5);
    float p6 = __builtin_amdgcn_exp2f(a6), p7 = __builtin_amdgcn_exp2f(a7);
    l += ((p0 + p1) + (p2 + p3)) + ((p4 + p5) + (p6 + p7));
    u32 A = cvtpk(p0, p1);
    u32 B = cvtpk(p4, p5);
    u32 C = cvtpk(p2, p3);
    u32 D = cvtpk(p6, p7);
    u2v rAB = __builtin_amdgcn_permlane32_swap(A, B, false, false);
    u2v rCD = __builtin_amdgcn_permlane32_swap(C, D, false, false);
    union { s8v v; u32 wd[4]; } P;
    P.wd[0] = rAB[0]; P.wd[1] = rCD[0]; P.wd[2] = rAB[1]; P.wd[3] = rCD[1];
    return P.v;
  };

  // PV for one k-slice group: o[dt] += V^T . P
  auto pv16 = [&](const char* bV, int ks, s8v P, f16v* o) {
    __builtin_amdgcn_s_setprio(1);
    #pragma unroll
    for (int dt = 0; dt < 4; ++dt) {
      const int d = dt * 32 + q5;
      const int row = d & 63;
      const int col = ((dt >> 1) * 128 + ks * 32 + h * 16) ^ ((row & 15) << 4);
      s8v vf = *(const s8v*)(bV + row * 256 + col);
      o[dt] = __builtin_amdgcn_mfma_f32_32x32x16_bf16(vf, P, o[dt], 0, 0, 0);
    }
    __builtin_amdgcn_s_setprio(0);
  };

  f16v o[4];
  #pragma unroll
  for (int dt = 0; dt < 4; ++dt)
    o[dt] = (f16v){0,0,0,0,0,0,0,0,0,0,0,0,0,0,0,0};
  float lsum = 0.f;
  s8v P0 = (s8v){0,0,0,0,0,0,0,0}, P1 = P0, P2 = P0, P3 = P0;

  stageK(0, 0);
  asm volatile("s_waitcnt vmcnt(0)" ::: "memory");
  __builtin_amdgcn_sched_barrier(0);
  __builtin_amdgcn_s_barrier();

  #pragma unroll 1
  for (int t = 0; t < 32; ++t) {
    // issue: K one ahead, V zero ahead
    if (t + 1 < 32) stageK((t + 1) & 1, t + 1);
    stageV(t & 1, t);

    // ---- QK(t): S^T[k][q] = K . Q^T (compiler-paced lgkmcnt)
    const char* bK = Kbuf(t & 1);
    f16v s0v = (f16v){0,0,0,0,0,0,0,0,0,0,0,0,0,0,0,0};
    f16v s1v = (f16v){0,0,0,0,0,0,0,0,0,0,0,0,0,0,0,0};
    __builtin_amdgcn_s_setprio(1);
    #pragma unroll
    for (int dc = 0; dc < 8; ++dc) {
      s8v kf0 = *(const s8v*)(bK + (q5) * 256      + ((dc * 32 + h * 16) ^ ((q5 & 15) << 4)));
      s8v kf1 = *(const s8v*)(bK + (32 + q5) * 256 + ((dc * 32 + h * 16) ^ ((q5 & 15) << 4)));
      s0v = __builtin_amdgcn_mfma_f32_32x32x16_bf16(kf0, qf[dc], s0v, 0, 0, 0);
      s1v = __builtin_amdgcn_mfma_f32_32x32x16_bf16(kf1, qf[dc], s1v, 0, 0, 0);
    }
    __builtin_amdgcn_s_setprio(0);

    // ---- PV(t-1): independent of QK(t)/SM(t); V from buf (t-1)&1
    if (t > 0) {
      const char* bV = Vbuf((t - 1) & 1);
      pv16(bV, 0, P0, o);
      pv16(bV, 1, P1, o);
      pv16(bV, 2, P2, o);
      pv16(bV, 3, P3, o);
    }

    // ---- SM(t): scores -> P regs for next tile's PV
    P0 = expfrag8(s0v[0], s0v[1], s0v[2], s0v[3], s0v[4], s0v[5], s0v[6], s0v[7], lsum);
    P1 = expfrag8(s0v[8], s0v[9], s0v[10], s0v[11], s0v[12], s0v[13], s0v[14], s0v[15], lsum);
    P2 = expfrag8(s1v[0], s1v[1], s1v[2], s1v[3], s1v[4], s1v[5], s1v[6], s1v[7], lsum);
    P3 = expfrag8(s1v[8], s1v[9], s1v[10], s1v[11], s1v[12], s1v[13], s1v[14], s1v[15], lsum);

    // ---- tile convergence: my ds_reads done; staged tiles resident
    asm volatile("s_waitcnt lgkmcnt(0)" ::: "memory");
    __builtin_amdgcn_sched_barrier(0);
    asm volatile("s_waitcnt vmcnt(0)" ::: "memory");
    __builtin_amdgcn_sched_barrier(0);
    __builtin_amdgcn_s_barrier();
  }

  // ---- epilogue PV(31): V(31) staged during tile 31, resident
  {
    const char* bV = Vbuf(31 & 1);
    pv16(bV, 0, P0, o);
    pv16(bV, 1, P1, o);
    pv16(bV, 2, P2, o);
    pv16(bV, 3, P3, o);
  }

  // ---- combine the two k-slices via (dead) LDS ----------------------------
  lsum += __shfl_xor(lsum, 32);
  if (h == 0) lx[slice][sub][q5] = lsum;
  float* cb = (float*)lds;                 // 64 KB: [sub][128 e][32 q]
  __syncthreads();
  if (slice == 1) {
    #pragma unroll
    for (int dt = 0; dt < 4; ++dt)
      #pragma unroll
      for (int r = 0; r < 16; ++r) {
        const int e = dt * 32 + (r & 3) + 8 * (r >> 2) + 4 * h;
        cb[sub * 4096 + e * 32 + q5] = o[dt][r];
      }
  }
  __syncthreads();
  if (slice == 0) {
    const float rinv = 1.0f / (lx[0][sub][q5] + lx[1][sub][q5]);
    float* ob = out + (size_t)b * NE * NS;
    #pragma unroll
    for (int dt = 0; dt < 4; ++dt)
      #pragma unroll
      for (int r = 0; r < 16; ++r) {
        const int e = dt * 32 + (r & 3) + 8 * (r >> 2) + 4 * h;
        ob[(size_t)e * NS + qw + q5] =
            (o[dt][r] + cb[sub * 4096 + e * 32 + q5]) * rinv;
      }
  }
}

extern "C" void kernel_launch(void* const* d_in, const int* in_sizes, int n_in,
                              void* d_out, int out_size, void* d_ws, size_t ws_size,
                              hipStream_t stream) {
  (void)in_sizes; (void)n_in; (void)out_size; (void)ws_size;
  const float* x  = (const float*)d_in[0];
  const float* Wq = (const float*)d_in[1];
  const float* bq = (const float*)d_in[2];
  const float* Wk = (const float*)d_in[3];
  const float* bk = (const float*)d_in[4];
  const float* Wv = (const float*)d_in[5];
  const float* bv = (const float*)d_in[6];
  float* out = (float*)d_out;

  ushort* Qn = (ushort*)d_ws;                      // [B][S][D] bf16, 8 MB
  ushort* Kn = Qn + (size_t)NB * NS * NE;          // [B][S][D] bf16, 8 MB
  ushort* Vt = Kn + (size_t)NB * NS * NE;          // [B][D][S] bf16, 8 MB

  proj_gemm<<<dim3(NS / 64 * NB), 256, 0, stream>>>(x, Wq, bq, Wk, bk, Wv, bv, Qn, Kn, Vt);
  attn_kernel<<<dim3(NS / 128 * NB), 512, 0, stream>>>(Qn, Kn, Vt, out);
}